// Round 14
// baseline (118.487 us; speedup 1.0000x reference)
//
#include <hip/hip_runtime.h>
#include <hip/hip_bf16.h>

typedef int i32x4 __attribute__((ext_vector_type(4)));
typedef int i32x8 __attribute__((ext_vector_type(8)));
typedef float f32x4 __attribute__((ext_vector_type(4)));

#define KD 768
#define BDIM 4096
#define E8M0_1_8TH 124   // 2^(124-127) = 1/8

__device__ inline unsigned char f32_to_e4m3(float f) {
    int p = __builtin_amdgcn_cvt_pk_fp8_f32(f, f, 0, false);
    return (unsigned char)(p & 0xFF);
}

// ---------------- Kernel 1: row-normalize fp32 -> fp8 e4m3, pre-scaled x8 ----------------
__global__ __launch_bounds__(256) void normalize_rows_fp8(
    const float* __restrict__ x, unsigned char* __restrict__ xn)
{
    const int row = blockIdx.x;
    const int t = threadIdx.x;
    const float* xr = x + (long)row * KD;

    float v[3];
    float ss = 0.f;
#pragma unroll
    for (int i = 0; i < 3; ++i) {
        v[i] = xr[t + 256 * i];
        ss += v[i] * v[i];
    }
#pragma unroll
    for (int off = 32; off > 0; off >>= 1) ss += __shfl_down(ss, off);
    __shared__ float wss[4];
    const int lane = t & 63, wv = t >> 6;
    if (lane == 0) wss[wv] = ss;
    __syncthreads();
    const float tot = wss[0] + wss[1] + wss[2] + wss[3];
    const float inv = 8.0f / fmaxf(sqrtf(tot), 1e-8f);
#pragma unroll
    for (int i = 0; i < 3; ++i)
        xn[(long)row * KD + t + 256 * i] = f32_to_e4m3(v[i] * inv);
}

// ---------------- Kernel 2: row-panel MX-fp8 GEMM — 4-KB write runs, no LDS ----------
// Block = 16 output rows x 4096 cols; grid 256 = 1/CU. A (16 x 768 fp8) in regs.
// B read directly from L2 per-lane (no LDS, no barriers, no vmcnt chains — waves
// fully independent). Wave w owns cols [w*512, w*512+512): acc[32] f32x4 (128 VGPR,
// fully unrolled), then stores: per output row, 32 offset-folded float2x16 stores
// form a CONTIGUOUS 4-KB run; 8 waves jointly cover the full 32-KB row.
// L2 line use: q0/q1 (and q2/q3) lo+hi loads consume full 64-B lines -> no over-fetch.
__global__ __launch_bounds__(512, 2) void sim_gemm_rowpanel(
    const unsigned char* __restrict__ Xn,
    const float* __restrict__ fcw, const float* __restrict__ fcb,
    float* __restrict__ out)
{
    const int tid = threadIdx.x;
    const int wv  = tid >> 6;    // 0..7
    const int ln  = tid & 63;
    const int fr  = ln & 15;
    const int q   = ln >> 4;     // 0..3

    const int bi = blockIdx.x;            // 0..255
    const long Arow0 = (long)bi * 16;
    const int  wcol0 = wv * 512;

    // --- A fragments: one M-frag (rows Arow0..+15), 6 kk, 48 VGPR ---
    i32x8 aF[6];
    {
        const unsigned char* pa = Xn + (Arow0 + fr) * (long)KD + q * 32;
#pragma unroll
        for (int kk = 0; kk < 6; ++kk) {
            i32x4 lo = *(const i32x4*)(pa + kk * 128);
            i32x4 hi = *(const i32x4*)(pa + kk * 128 + 16);
            aF[kk] = __builtin_shufflevector(lo, hi, 0, 1, 2, 3, 4, 5, 6, 7);
        }
    }

    // --- accumulate 32 col-frags, B straight from global (L2-resident) ---
    f32x4 acc[32];
    const unsigned char* pb0 = Xn + ((long)wcol0 + fr) * KD + q * 32;
#pragma unroll
    for (int cf = 0; cf < 32; ++cf) {
        const unsigned char* pb = pb0 + (long)cf * 16 * KD;
        f32x4 a = {};
#pragma unroll
        for (int kk = 0; kk < 6; ++kk) {
            i32x4 lo = *(const i32x4*)(pb + kk * 128);
            i32x4 hi = *(const i32x4*)(pb + kk * 128 + 16);
            i32x8 bv = __builtin_shufflevector(lo, hi, 0, 1, 2, 3, 4, 5, 6, 7);
            a = __builtin_amdgcn_mfma_scale_f32_16x16x128_f8f6f4(
                aF[kk], bv, a, 0, 0, 0, E8M0_1_8TH, 0, E8M0_1_8TH);
        }
        acc[cf] = a;
    }

    // --- epilogue: fused Linear(1,2); per row, 32 stores walk a contiguous 4-KB run ---
    const float w0 = fcw[0], w1 = fcw[1];
    const float c0 = fcb[0], c1 = fcb[1];
#pragma unroll
    for (int rr = 0; rr < 4; ++rr) {
        const long row = Arow0 + q * 4 + rr;
        float* po = out + (row * BDIM + wcol0 + fr) * 2;
#pragma unroll
        for (int cf = 0; cf < 32; ++cf) {
            const float sv = acc[cf][rr];
            *(float2*)(po + cf * 32) =
                make_float2(fmaf(sv, w0, c0), fmaf(sv, w1, c1));
        }
    }
}

extern "C" void kernel_launch(void* const* d_in, const int* in_sizes, int n_in,
                              void* d_out, int out_size, void* d_ws, size_t ws_size,
                              hipStream_t stream) {
    const float* x   = (const float*)d_in[0];
    const float* fcw = (const float*)d_in[1];
    const float* fcb = (const float*)d_in[2];
    float* out = (float*)d_out;

    unsigned char* xn = (unsigned char*)d_ws;  // 4096*768*1B = 3.1 MB

    normalize_rows_fp8<<<BDIM, 256, 0, stream>>>(x, xn);

    sim_gemm_rowpanel<<<BDIM / 16, 512, 0, stream>>>(xn, fcw, fcb, out);
}

// Round 15
// 107.949 us; speedup vs baseline: 1.0976x; 1.0976x over previous
//
#include <hip/hip_runtime.h>
#include <hip/hip_bf16.h>

typedef int i32x4 __attribute__((ext_vector_type(4)));
typedef int i32x8 __attribute__((ext_vector_type(8)));
typedef float f32x4 __attribute__((ext_vector_type(4)));

#define KD 768
#define BDIM 4096
#define E8M0_1_8TH 124   // 2^(124-127) = 1/8

__device__ inline unsigned char f32_to_e4m3(float f) {
    int p = __builtin_amdgcn_cvt_pk_fp8_f32(f, f, 0, false);
    return (unsigned char)(p & 0xFF);
}

// ---------------- Kernel 1: row-normalize fp32 -> fp8 e4m3, pre-scaled x8 ----------------
__global__ __launch_bounds__(256) void normalize_rows_fp8(
    const float* __restrict__ x, unsigned char* __restrict__ xn)
{
    const int row = blockIdx.x;
    const int t = threadIdx.x;
    const float* xr = x + (long)row * KD;

    float v[3];
    float ss = 0.f;
#pragma unroll
    for (int i = 0; i < 3; ++i) {
        v[i] = xr[t + 256 * i];
        ss += v[i] * v[i];
    }
#pragma unroll
    for (int off = 32; off > 0; off >>= 1) ss += __shfl_down(ss, off);
    __shared__ float wss[4];
    const int lane = t & 63, wv = t >> 6;
    if (lane == 0) wss[wv] = ss;
    __syncthreads();
    const float tot = wss[0] + wss[1] + wss[2] + wss[3];
    const float inv = 8.0f / fmaxf(sqrtf(tot), 1e-8f);
#pragma unroll
    for (int i = 0; i < 3; ++i)
        xn[(long)row * KD + t + 256 * i] = f32_to_e4m3(v[i] * inv);
}

// ---------------- Kernel 2: row-panel MX-fp8 GEMM, register-bounded (R14 fixed) -------
// Block = 16 rows x 2048 cols; grid (2,256) = 512 blocks = 2/CU; 8 waves/block.
// Wave owns 256 cols = 16 col-frags. Per frag: 12 L2 loads (16 full 128-B lines),
// 6-kk MFMA chain into ONE f32x4, stores fused immediately (4 float2/lane).
// #pragma unroll 1 bounds live state: aF(48) + bv pipe + acc + addr ~= 100 VGPR
// -> no scratch (R14's failure), 4 waves/SIMD. No LDS, no barriers, no waitcnt:
// waves fully independent; 16 waves/CU TLP hides load latency + store-ack drains.
// Per output row, block writes 16 KB contiguous (8 waves x 2 KB adjacent).
__global__ __launch_bounds__(512, 4) void sim_gemm_panel(
    const unsigned char* __restrict__ Xn,
    const float* __restrict__ fcw, const float* __restrict__ fcb,
    float* __restrict__ out)
{
    const int tid = threadIdx.x;
    const int wv  = tid >> 6;    // 0..7
    const int ln  = tid & 63;
    const int fr  = ln & 15;
    const int q   = ln >> 4;     // 0..3

    const long Arow0 = (long)blockIdx.y * 16;
    const int  col0  = blockIdx.x * 2048 + wv * 256;

    // --- A fragments: one M-frag (rows Arow0..+15), 6 kk, 48 VGPR ---
    i32x8 aF[6];
    {
        const unsigned char* pa = Xn + (Arow0 + fr) * (long)KD + q * 32;
#pragma unroll
        for (int kk = 0; kk < 6; ++kk) {
            i32x4 lo = *(const i32x4*)(pa + kk * 128);
            i32x4 hi = *(const i32x4*)(pa + kk * 128 + 16);
            aF[kk] = __builtin_shufflevector(lo, hi, 0, 1, 2, 3, 4, 5, 6, 7);
        }
    }

    const float w0 = fcw[0], w1 = fcw[1];
    const float c0 = fcb[0], c1 = fcb[1];

    const unsigned char* pb0 = Xn + ((long)col0 + fr) * KD + q * 32;

#pragma unroll 1
    for (int cf = 0; cf < 16; ++cf) {
        const unsigned char* pb = pb0 + (long)cf * 16 * KD;

        f32x4 acc = {};
#pragma unroll
        for (int kk = 0; kk < 6; ++kk) {
            i32x4 lo = *(const i32x4*)(pb + kk * 128);
            i32x4 hi = *(const i32x4*)(pb + kk * 128 + 16);
            i32x8 bv = __builtin_shufflevector(lo, hi, 0, 1, 2, 3, 4, 5, 6, 7);
            acc = __builtin_amdgcn_mfma_scale_f32_16x16x128_f8f6f4(
                aF[kk], bv, acc, 0, 0, 0, E8M0_1_8TH, 0, E8M0_1_8TH);
        }

        // fused store: 4 float2 per lane; wave covers 16 rows x 128 B this frag,
        // walking a contiguous 2-KB run per row across the cf loop.
        const int col = col0 + cf * 16 + fr;
#pragma unroll
        for (int rr = 0; rr < 4; ++rr) {
            const long row = Arow0 + q * 4 + rr;
            const float sv = acc[rr];
            *(float2*)&out[(row * BDIM + col) * 2] =
                make_float2(fmaf(sv, w0, c0), fmaf(sv, w1, c1));
        }
    }
}

extern "C" void kernel_launch(void* const* d_in, const int* in_sizes, int n_in,
                              void* d_out, int out_size, void* d_ws, size_t ws_size,
                              hipStream_t stream) {
    const float* x   = (const float*)d_in[0];
    const float* fcw = (const float*)d_in[1];
    const float* fcb = (const float*)d_in[2];
    float* out = (float*)d_out;

    unsigned char* xn = (unsigned char*)d_ws;  // 4096*768*1B = 3.1 MB

    normalize_rows_fp8<<<BDIM, 256, 0, stream>>>(x, xn);

    dim3 grid(2, 256);  // col half x row panel = 512 blocks, 2/CU
    sim_gemm_panel<<<grid, 512, 0, stream>>>(xn, fcw, fcb, out);
}

// Round 16
// 103.709 us; speedup vs baseline: 1.1425x; 1.0409x over previous
//
#include <hip/hip_runtime.h>
#include <hip/hip_bf16.h>

typedef int i32x4 __attribute__((ext_vector_type(4)));
typedef int i32x8 __attribute__((ext_vector_type(8)));
typedef float f32x4 __attribute__((ext_vector_type(4)));

#define KD 768
#define BDIM 4096
#define E8M0_1_8TH 124   // 2^(124-127) = 1/8
#define LDA_PAD 784      // 768+16: row bank-shift 4 words -> fr vs fr+8 2-way (free, m136)

__device__ inline unsigned char f32_to_e4m3(float f) {
    int p = __builtin_amdgcn_cvt_pk_fp8_f32(f, f, 0, false);
    return (unsigned char)(p & 0xFF);
}

// ---------------- Kernel 1: row-normalize fp32 -> fp8 e4m3, pre-scaled x8 ----------------
__global__ __launch_bounds__(256) void normalize_rows_fp8(
    const float* __restrict__ x, unsigned char* __restrict__ xn)
{
    const int row = blockIdx.x;
    const int t = threadIdx.x;
    const float* xr = x + (long)row * KD;

    float v[3];
    float ss = 0.f;
#pragma unroll
    for (int i = 0; i < 3; ++i) {
        v[i] = xr[t + 256 * i];
        ss += v[i] * v[i];
    }
#pragma unroll
    for (int off = 32; off > 0; off >>= 1) ss += __shfl_down(ss, off);
    __shared__ float wss[4];
    const int lane = t & 63, wv = t >> 6;
    if (lane == 0) wss[wv] = ss;
    __syncthreads();
    const float tot = wss[0] + wss[1] + wss[2] + wss[3];
    const float inv = 8.0f / fmaxf(sqrtf(tot), 1e-8f);
#pragma unroll
    for (int i = 0; i < 3; ++i)
        xn[(long)row * KD + t + 256 * i] = f32_to_e4m3(v[i] * inv);
}

// ---------------- Kernel 2: row-panel MX-fp8 GEMM, A-in-LDS (R15 spill fixed) ----------
// Block = 16 rows x 2048 cols; grid (2,256) = 512 blocks = 2/CU; 8 waves/block.
// A-panel (16 x 768 B) staged to LDS once (padded rows), read per-kk via ds_read_b128
// -> NO vector array lives across the frag-loop backedge -> no spill (R15's failure).
// B read directly from L2 per lane (FETCH_SIZE 9MB proven, R15). Per frag:
// 12 ds_read + 12 L2 loads + 6-kk MFMA chain + 8 fused float2 stores -> stores
// trickle continuously (smooth-write test). No inter-wave sync after the one barrier.
// Co-resident block pair (bx=0/1) shares the A-panel rows -> L1/L2 hot.
__global__ __launch_bounds__(512, 4) void sim_gemm_panel(
    const unsigned char* __restrict__ Xn,
    const float* __restrict__ fcw, const float* __restrict__ fcb,
    float* __restrict__ out)
{
    __shared__ __align__(16) unsigned char Ald[16 * LDA_PAD];  // 12.25 KB

    const int tid = threadIdx.x;
    const int wv  = tid >> 6;    // 0..7
    const int ln  = tid & 63;
    const int fr  = ln & 15;
    const int q   = ln >> 4;     // 0..3

    const long Arow0 = (long)blockIdx.y * 16;
    const int  col0  = blockIdx.x * 2048 + wv * 256;

    // --- stage A panel to LDS: 768 chunks of 16 B over 512 threads ---
    for (int c = tid; c < 768; c += 512) {
        const int row = c / 48;            // 48 chunks per 768-B row
        const int off = (c % 48) * 16;
        *(i32x4*)&Ald[row * LDA_PAD + off] =
            *(const i32x4*)(Xn + (Arow0 + row) * (long)KD + off);
    }
    __syncthreads();

    const float w0 = fcw[0], w1 = fcw[1];
    const float c0 = fcb[0], c1 = fcb[1];

    const unsigned char* pb0 = Xn + ((long)col0 + fr) * KD + q * 32;
    const int aoff = fr * LDA_PAD + q * 32;

#pragma unroll 1
    for (int cf = 0; cf < 16; ++cf) {
        const unsigned char* pb = pb0 + (long)cf * 16 * KD;

        f32x4 acc = {};
#pragma unroll
        for (int kk = 0; kk < 6; ++kk) {
            // A from LDS (identical bytes to R15's aF[kk])
            i32x4 alo = *(const i32x4*)&Ald[aoff + kk * 128];
            i32x4 ahi = *(const i32x4*)&Ald[aoff + kk * 128 + 16];
            i32x8 av  = __builtin_shufflevector(alo, ahi, 0, 1, 2, 3, 4, 5, 6, 7);
            // B from global (L2-resident)
            i32x4 blo = *(const i32x4*)(pb + kk * 128);
            i32x4 bhi = *(const i32x4*)(pb + kk * 128 + 16);
            i32x8 bv  = __builtin_shufflevector(blo, bhi, 0, 1, 2, 3, 4, 5, 6, 7);
            acc = __builtin_amdgcn_mfma_scale_f32_16x16x128_f8f6f4(
                av, bv, acc, 0, 0, 0, E8M0_1_8TH, 0, E8M0_1_8TH);
        }

        // fused store: 4 float2/lane; wave covers 16 rows x 128 B this frag,
        // walking a contiguous 2-KB run per row across cf.
        const int col = col0 + cf * 16 + fr;
#pragma unroll
        for (int rr = 0; rr < 4; ++rr) {
            const long row = Arow0 + q * 4 + rr;
            const float sv = acc[rr];
            *(float2*)&out[(row * BDIM + col) * 2] =
                make_float2(fmaf(sv, w0, c0), fmaf(sv, w1, c1));
        }
    }
}

extern "C" void kernel_launch(void* const* d_in, const int* in_sizes, int n_in,
                              void* d_out, int out_size, void* d_ws, size_t ws_size,
                              hipStream_t stream) {
    const float* x   = (const float*)d_in[0];
    const float* fcw = (const float*)d_in[1];
    const float* fcb = (const float*)d_in[2];
    float* out = (float*)d_out;

    unsigned char* xn = (unsigned char*)d_ws;  // 4096*768*1B = 3.1 MB

    normalize_rows_fp8<<<BDIM, 256, 0, stream>>>(x, xn);

    dim3 grid(2, 256);  // col half x row panel = 512 blocks, 2/CU
    sim_gemm_panel<<<grid, 512, 0, stream>>>(xn, fcw, fcb, out);
}

// Round 17
// 42.357 us; speedup vs baseline: 2.7973x; 2.4484x over previous
//
#include <hip/hip_runtime.h>
#include <hip/hip_bf16.h>

typedef int i32x4 __attribute__((ext_vector_type(4)));
typedef int i32x8 __attribute__((ext_vector_type(8)));
typedef float f32x4 __attribute__((ext_vector_type(4)));

#define KD 768
#define BDIM 4096
#define NSTRIP 16        // 512 cols / 32
#define E8M0_1_8TH 124   // 2^(124-127) = 1/8
#define BLDS 24576       // 32 cols x 768 K bytes

#define GLOAD_LDS16(gptr, lptr)                                             \
    __builtin_amdgcn_global_load_lds(                                       \
        (const __attribute__((address_space(1))) unsigned int*)(gptr),      \
        (__attribute__((address_space(3))) unsigned int*)(lptr), 16, 0, 0)

#define FBAR() asm volatile("s_barrier" ::: "memory")
#define SCHED_FENCE() __builtin_amdgcn_sched_barrier(0)

// ---------------- Kernel 1: row-normalize fp32 -> fp8 e4m3 (x8), vectorized ----------
// 192 threads: thread t owns elements 4t..4t+3 (float4 load, packed-int store).
__global__ __launch_bounds__(192) void normalize_rows_fp8(
    const float* __restrict__ x, unsigned char* __restrict__ xn)
{
    const int row = blockIdx.x;
    const int t = threadIdx.x;

    const float4 v = *(const float4*)(x + (long)row * KD + 4 * t);
    float ss = v.x * v.x + v.y * v.y + v.z * v.z + v.w * v.w;
#pragma unroll
    for (int off = 32; off > 0; off >>= 1) ss += __shfl_down(ss, off);
    __shared__ float wss[3];
    const int lane = t & 63, wv = t >> 6;
    if (lane == 0) wss[wv] = ss;
    __syncthreads();
    const float tot = wss[0] + wss[1] + wss[2];
    const float inv = 8.0f / fmaxf(sqrtf(tot), 1e-8f);

    const int p0 = __builtin_amdgcn_cvt_pk_fp8_f32(v.x * inv, v.y * inv, 0, false);
    const int p1 = __builtin_amdgcn_cvt_pk_fp8_f32(v.z * inv, v.w * inv, 0, false);
    *(int*)(xn + (long)row * KD + 4 * t) = (p0 & 0xFFFF) | (p1 << 16);
}

// ---------------- Kernel 2: streaming MX-fp8 GEMM, 2 blocks/CU, float4 stores --------
// R11-identical skeleton. Changes: (1) epilogue pairs lanes fr/fr^1 via shfl_xor so
// each lane stores one float4 (16 B) per row-pair -> 2 stores/strip/lane (was 4);
// (2) vmcnt(4) -> vmcnt(2) (FIFO: 2 youngest = this strip's stores).
__global__ __launch_bounds__(512, 4) void sim_gemm_stream(
    const unsigned char* __restrict__ Xn,
    const float* __restrict__ fcw, const float* __restrict__ fcb,
    float* __restrict__ out)
{
    __shared__ __align__(16) unsigned char Bb[2][BLDS];  // 2 x 24 KB

    const int tid = threadIdx.x;
    const int wv  = tid >> 6;    // 0..7
    const int ln  = tid & 63;
    const int wm  = wv >> 1;     // 0..3 (M group, 16 rows)
    const int wn  = wv & 1;      // 0..1 (N group, 16 cols)
    const int fr  = ln & 15;
    const int q   = ln >> 4;     // 0..3

    const int jc = blockIdx.x;   // 0..7   col chunk (512 cols)
    const int bi = blockIdx.y;   // 0..63  row chunk (64 rows)
    const long Arow0 = (long)bi * 64;
    const long Bcol0 = (long)jc * 512;

    // --- B staging precompute: dest byte d = i*8192 + tid*16, i<3.
    //     d -> kk=d>>12, o=(d>>11)&1, col=(d>>6)&31, q=(d>>4)&3
    //     source: Xn row (Bcol0+s*32+col), k byte = kk*128+q*32+o*16 (16B contiguous)
    int scol[3], skoff[3];
#pragma unroll
    for (int i = 0; i < 3; ++i) {
        const int d = i * 8192 + tid * 16;
        scol[i]  = (d >> 6) & 31;
        skoff[i] = ((d >> 12) << 7) + (((d >> 4) & 3) << 5) + (((d >> 11) & 1) << 4);
    }

#define ISSUE_B(s) do {                                                      \
        _Pragma("unroll")                                                    \
        for (int i_ = 0; i_ < 3; ++i_) {                                     \
            const unsigned char* g_ = Xn                                     \
                + (Bcol0 + (s) * 32 + scol[i_]) * (long)KD + skoff[i_];      \
            unsigned char* l_ = &Bb[(s) & 1][0] + i_ * 8192 + wv * 1024;     \
            GLOAD_LDS16(g_, l_);                                             \
        }                                                                    \
    } while (0)

    // --- A fragments: global -> registers, once. 1 M-frag x 6 kk x 32 B = 48 VGPR.
    i32x8 aF[6];
    {
        const unsigned char* pa = Xn + (Arow0 + wm * 16 + fr) * (long)KD + q * 32;
#pragma unroll
        for (int kk = 0; kk < 6; ++kk) {
            i32x4 lo = *(const i32x4*)(pa + kk * 128);
            i32x4 hi = *(const i32x4*)(pa + kk * 128 + 16);
            aF[kk] = __builtin_shufflevector(lo, hi, 0, 1, 2, 3, 4, 5, 6, 7);
        }
    }

    const float w0 = fcw[0], w1 = fcw[1];
    const float c0 = fcb[0], c1 = fcb[1];

    // --- prologue: stage strip 0; drain once; sync ---
    ISSUE_B(0);
    asm volatile("s_waitcnt vmcnt(0)" ::: "memory");
    FBAR();

    const int colbase = (int)Bcol0 + wn * 16 + fr;
    const long rowb   = Arow0 + wm * 16 + q * 4;

    for (int s = 0; s < NSTRIP; ++s) {
        const int bb = s & 1;

        if (s + 1 < NSTRIP) ISSUE_B(s + 1);
        SCHED_FENCE();  // pin order: [3 staging loads] before this strip's stores

        // compute strip: 6 kk slices, acc fresh per strip
        f32x4 acc = {};
#pragma unroll
        for (int kk = 0; kk < 6; ++kk) {
            const int bo = kk * 4096 + (wn * 16 + fr) * 64 + q * 16;
            i32x4 lo = *(const i32x4*)&Bb[bb][bo];
            i32x4 hi = *(const i32x4*)&Bb[bb][bo + 2048];
            i32x8 bv = __builtin_shufflevector(lo, hi, 0, 1, 2, 3, 4, 5, 6, 7);
            __builtin_amdgcn_s_setprio(1);
            acc = __builtin_amdgcn_mfma_scale_f32_16x16x128_f8f6f4(
                aF[kk], bv, acc, 0, 0, 0, E8M0_1_8TH, 0, E8M0_1_8TH);
            __builtin_amdgcn_s_setprio(0);
        }

        // paired float4 stores: lanes fr (even) / fr^1 (odd) exchange rows via
        // shfl_xor; even lane stores rows rr=0,1; odd lane rows rr=2,3, both at
        // the pair's even column. 2 x 16 B per lane (was 4 x 8 B).
        const int col = colbase + s * 32;          // parity = fr&1
        float2 v[4], ex[4];
#pragma unroll
        for (int rr = 0; rr < 4; ++rr) {
            const float sv = acc[rr];
            v[rr] = make_float2(fmaf(sv, w0, c0), fmaf(sv, w1, c1));
            double d = __shfl_xor(__builtin_bit_cast(double, v[rr]), 1);
            ex[rr] = __builtin_bit_cast(float2, d);
        }
        if ((ln & 1) == 0) {
#pragma unroll
            for (int rr = 0; rr < 2; ++rr) {
                const long row = rowb + rr;
                *(float4*)&out[(row * BDIM + col) * 2] =
                    make_float4(v[rr].x, v[rr].y, ex[rr].x, ex[rr].y);
            }
        } else {
#pragma unroll
            for (int rr = 2; rr < 4; ++rr) {
                const long row = rowb + rr;
                *(float4*)&out[(row * BDIM + col - 1) * 2] =
                    make_float4(ex[rr].x, ex[rr].y, v[rr].x, v[rr].y);
            }
        }

        if (s + 1 < NSTRIP) {
            // FIFO: 2 youngest ops are this strip's stores; <=2 outstanding
            // => B(s+1)'s 3 loads (older) landed. Never drains the store stream.
            asm volatile("s_waitcnt vmcnt(2)" ::: "memory");
            FBAR();  // next buffer visible; prior buffer reads complete
        }
    }

#undef ISSUE_B
}

extern "C" void kernel_launch(void* const* d_in, const int* in_sizes, int n_in,
                              void* d_out, int out_size, void* d_ws, size_t ws_size,
                              hipStream_t stream) {
    const float* x   = (const float*)d_in[0];
    const float* fcw = (const float*)d_in[1];
    const float* fcb = (const float*)d_in[2];
    float* out = (float*)d_out;

    unsigned char* xn = (unsigned char*)d_ws;  // 4096*768*1B = 3.1 MB

    normalize_rows_fp8<<<BDIM, 192, 0, stream>>>(x, xn);

    dim3 grid(8, 64);  // jc x bi = 512 blocks, 2/CU
    sim_gemm_stream<<<grid, 512, 0, stream>>>(xn, fcw, fcb, out);
}

// Round 18
// 39.614 us; speedup vs baseline: 2.9910x; 1.0692x over previous
//
#include <hip/hip_runtime.h>
#include <hip/hip_bf16.h>

typedef int i32x4 __attribute__((ext_vector_type(4)));
typedef int i32x8 __attribute__((ext_vector_type(8)));
typedef float f32x4 __attribute__((ext_vector_type(4)));

#define KD 768
#define BDIM 4096
#define NSTRIP 16        // 512 cols / 32
#define E8M0_1_8TH 124   // 2^(124-127) = 1/8
#define BLDS 24576       // 32 cols x 768 K bytes

#define GLOAD_LDS16(gptr, lptr)                                             \
    __builtin_amdgcn_global_load_lds(                                       \
        (const __attribute__((address_space(1))) unsigned int*)(gptr),      \
        (__attribute__((address_space(3))) unsigned int*)(lptr), 16, 0, 0)

#define FBAR() asm volatile("s_barrier" ::: "memory")
#define SCHED_FENCE() __builtin_amdgcn_sched_barrier(0)

__device__ inline unsigned char f32_to_e4m3(float f) {
    int p = __builtin_amdgcn_cvt_pk_fp8_f32(f, f, 0, false);
    return (unsigned char)(p & 0xFF);
}

// ---------------- Kernel 1: row-normalize fp32 -> fp8 e4m3, pre-scaled x8 ----------------
__global__ __launch_bounds__(256) void normalize_rows_fp8(
    const float* __restrict__ x, unsigned char* __restrict__ xn)
{
    const int row = blockIdx.x;
    const int t = threadIdx.x;
    const float* xr = x + (long)row * KD;

    float v[3];
    float ss = 0.f;
#pragma unroll
    for (int i = 0; i < 3; ++i) {
        v[i] = xr[t + 256 * i];
        ss += v[i] * v[i];
    }
#pragma unroll
    for (int off = 32; off > 0; off >>= 1) ss += __shfl_down(ss, off);
    __shared__ float wss[4];
    const int lane = t & 63, wv = t >> 6;
    if (lane == 0) wss[wv] = ss;
    __syncthreads();
    const float tot = wss[0] + wss[1] + wss[2] + wss[3];
    const float inv = 8.0f / fmaxf(sqrtf(tot), 1e-8f);
#pragma unroll
    for (int i = 0; i < 3; ++i)
        xn[(long)row * KD + t + 256 * i] = f32_to_e4m3(v[i] * inv);
}

// ---------------- Kernel 2: streaming MX-fp8 GEMM, 2 blocks/CU (session best) --------
// Block = 64 rows x 512 cols, grid 512 = 2/CU, LDS 48 KB/block, A-regs 48 VGPR,
// launch_bounds(512,4) -> 16 waves/CU = 4/SIMD. B streams in 16 strips of 32 cols
// via LDS dbuf; each strip's output stores immediately (streamed writes, no drain).
// 8 waves (4M x 2N): wave = 16 rows x 16 cols per strip; per strip per wave:
// 12 ds_read_b128, 6 MFMA(K=128), 4 float2 stores.
__global__ __launch_bounds__(512, 4) void sim_gemm_stream(
    const unsigned char* __restrict__ Xn,
    const float* __restrict__ fcw, const float* __restrict__ fcb,
    float* __restrict__ out)
{
    __shared__ __align__(16) unsigned char Bb[2][BLDS];  // 2 x 24 KB

    const int tid = threadIdx.x;
    const int wv  = tid >> 6;    // 0..7
    const int ln  = tid & 63;
    const int wm  = wv >> 1;     // 0..3 (M group, 16 rows)
    const int wn  = wv & 1;      // 0..1 (N group, 16 cols)
    const int fr  = ln & 15;
    const int q   = ln >> 4;     // 0..3

    const int jc = blockIdx.x;   // 0..7   col chunk (512 cols)
    const int bi = blockIdx.y;   // 0..63  row chunk (64 rows)
    const long Arow0 = (long)bi * 64;
    const long Bcol0 = (long)jc * 512;

    // --- B staging precompute: dest byte d = i*8192 + tid*16, i<3.
    //     d -> kk=d>>12, o=(d>>11)&1, col=(d>>6)&31, q=(d>>4)&3
    //     source: Xn row (Bcol0+s*32+col), k byte = kk*128+q*32+o*16 (16B contiguous)
    int scol[3], skoff[3];
#pragma unroll
    for (int i = 0; i < 3; ++i) {
        const int d = i * 8192 + tid * 16;
        scol[i]  = (d >> 6) & 31;
        skoff[i] = ((d >> 12) << 7) + (((d >> 4) & 3) << 5) + (((d >> 11) & 1) << 4);
    }

#define ISSUE_B(s) do {                                                      \
        _Pragma("unroll")                                                    \
        for (int i_ = 0; i_ < 3; ++i_) {                                     \
            const unsigned char* g_ = Xn                                     \
                + (Bcol0 + (s) * 32 + scol[i_]) * (long)KD + skoff[i_];      \
            unsigned char* l_ = &Bb[(s) & 1][0] + i_ * 8192 + wv * 1024;     \
            GLOAD_LDS16(g_, l_);                                             \
        }                                                                    \
    } while (0)

    // --- A fragments: global -> registers, once. 1 M-frag x 6 kk x 32 B = 48 VGPR.
    i32x8 aF[6];
    {
        const unsigned char* pa = Xn + (Arow0 + wm * 16 + fr) * (long)KD + q * 32;
#pragma unroll
        for (int kk = 0; kk < 6; ++kk) {
            i32x4 lo = *(const i32x4*)(pa + kk * 128);
            i32x4 hi = *(const i32x4*)(pa + kk * 128 + 16);
            aF[kk] = __builtin_shufflevector(lo, hi, 0, 1, 2, 3, 4, 5, 6, 7);
        }
    }

    const float w0 = fcw[0], w1 = fcw[1];
    const float c0 = fcb[0], c1 = fcb[1];

    // --- prologue: stage strip 0; drain once; sync ---
    ISSUE_B(0);
    asm volatile("s_waitcnt vmcnt(0)" ::: "memory");
    FBAR();

    const int colbase = (int)Bcol0 + wn * 16 + fr;
    const long rowb   = Arow0 + wm * 16 + q * 4;

    for (int s = 0; s < NSTRIP; ++s) {
        const int bb = s & 1;

        if (s + 1 < NSTRIP) ISSUE_B(s + 1);
        SCHED_FENCE();  // pin order: [3 staging loads] before this strip's stores

        // compute strip: 6 kk slices, acc fresh per strip
        f32x4 acc = {};
#pragma unroll
        for (int kk = 0; kk < 6; ++kk) {
            const int bo = kk * 4096 + (wn * 16 + fr) * 64 + q * 16;
            i32x4 lo = *(const i32x4*)&Bb[bb][bo];
            i32x4 hi = *(const i32x4*)&Bb[bb][bo + 2048];
            i32x8 bv = __builtin_shufflevector(lo, hi, 0, 1, 2, 3, 4, 5, 6, 7);
            __builtin_amdgcn_s_setprio(1);
            acc = __builtin_amdgcn_mfma_scale_f32_16x16x128_f8f6f4(
                aF[kk], bv, acc, 0, 0, 0, E8M0_1_8TH, 0, E8M0_1_8TH);
            __builtin_amdgcn_s_setprio(0);
        }

        // stream this strip's output: 4 float2 stores/lane
        const int col = colbase + s * 32;
#pragma unroll
        for (int rr = 0; rr < 4; ++rr) {
            const long row = rowb + rr;
            const float sv = acc[rr];
            *(float2*)&out[(row * BDIM + col) * 2] =
                make_float2(fmaf(sv, w0, c0), fmaf(sv, w1, c1));
        }

        if (s + 1 < NSTRIP) {
            // in-order vmcnt: the 4 youngest ops are this strip's stores;
            // <=4 outstanding => B(s+1)'s 3 loads (older) have landed.
            asm volatile("s_waitcnt vmcnt(4)" ::: "memory");
            FBAR();  // next buffer visible; prior buffer reads complete
        }
    }

#undef ISSUE_B
}

extern "C" void kernel_launch(void* const* d_in, const int* in_sizes, int n_in,
                              void* d_out, int out_size, void* d_ws, size_t ws_size,
                              hipStream_t stream) {
    const float* x   = (const float*)d_in[0];
    const float* fcw = (const float*)d_in[1];
    const float* fcb = (const float*)d_in[2];
    float* out = (float*)d_out;

    unsigned char* xn = (unsigned char*)d_ws;  // 4096*768*1B = 3.1 MB

    normalize_rows_fp8<<<BDIM, 256, 0, stream>>>(x, xn);

    dim3 grid(8, 64);  // jc x bi = 512 blocks, 2/CU
    sim_gemm_stream<<<grid, 512, 0, stream>>>(xn, fcw, fcb, out);
}